// Round 7
// baseline (519.403 us; speedup 1.0000x reference)
//
#include <hip/hip_runtime.h>
#include <hip/hip_bf16.h>

typedef __bf16 bf16_t;
typedef __bf16 bf16x8 __attribute__((ext_vector_type(8)));
typedef __bf16 bf16x4 __attribute__((ext_vector_type(4)));
typedef float f32x4 __attribute__((ext_vector_type(4)));

#define S_LEN 2048
#define HID   2048
#define NH    16
#define HD    128
#define QKVN  2304   // 2048 + 2*128
#define NEG_BIG (-30000.0f)

// direct global->LDS DMA, 16B per lane. lds dst must be the WAVE-UNIFORM base;
// HW adds lane*16 itself (m104). No LDS padding allowed in the covered range.
__device__ __forceinline__ void gld_lds16(const bf16_t* g, bf16_t* l) {
  __builtin_amdgcn_global_load_lds(
      (const __attribute__((address_space(1))) void*)((const void*)g),
      (__attribute__((address_space(3))) void*)((void*)l), 16, 0, 0);
}

// ---------------------------------------------------------------------------
// fp32 -> bf16 downcast, float4-vectorized.
// ---------------------------------------------------------------------------
__global__ __launch_bounds__(256) void cvt_f32_bf16_kernel(
    const float* __restrict__ in, bf16_t* __restrict__ out, int n)
{
  int i = (blockIdx.x * 256 + threadIdx.x) * 4;
  if (i < n) {
    float4 v = *(const float4*)(in + i);
    bf16x4 o;
    o[0] = (bf16_t)v.x; o[1] = (bf16_t)v.y; o[2] = (bf16_t)v.z; o[3] = (bf16_t)v.w;
    *(bf16x4*)(out + i) = o;
  }
}

// ---------------------------------------------------------------------------
// fp32 W[K][N] -> bf16 WT[N][K].
// ---------------------------------------------------------------------------
__global__ __launch_bounds__(256) void transpose_cvt_kernel(
    const float* __restrict__ in, bf16_t* __restrict__ out, int K, int N)
{
  int nc = threadIdx.x & 63;
  int kg = threadIdx.x >> 6;
  int n  = blockIdx.x * 64 + nc;
  int kb = blockIdx.y * 32 + kg * 8;
  bf16x8 v;
  #pragma unroll
  for (int i = 0; i < 8; ++i) v[i] = (bf16_t)in[(size_t)(kb + i) * N + n];
  *(bf16x8*)(out + (size_t)n * K + kb) = v;
}

// ---------------------------------------------------------------------------
// Extract V^T from qkv: vtg[b][d][s] = qkv[b*S+s][2176+d].
// ---------------------------------------------------------------------------
__global__ __launch_bounds__(256) void vt_extract_kernel(
    const bf16_t* __restrict__ qkv, bf16_t* __restrict__ vtg)
{
  int d  = threadIdx.x & 127;
  int sg = threadIdx.x >> 7;
  int b  = blockIdx.y;
  int s8 = blockIdx.x * 2 + sg;
  bf16x8 v;
  #pragma unroll
  for (int i = 0; i < 8; ++i)
    v[i] = qkv[((size_t)(b * S_LEN + s8 * 8 + i)) * QKVN + HID + HD + d];
  *(bf16x8*)(vtg + ((size_t)(b * HD + d)) * S_LEN + s8 * 8) = v;
}

// ---------------------------------------------------------------------------
// GEMM: C[M,N] = A[M,K] @ WT^T + bias (WT pre-transposed [N][K]).
// 128(M)x64(N) C-tile, BK=64, 4 waves as 2x2 (wave owns 64x32, acc[4][2]).
// Small tile -> grid 1024-1152 blocks = 4-4.5 blocks/CU co-resident (the
// m102 shape-curve lever). DMA staging + xor chunk swizzle as before.
// ---------------------------------------------------------------------------
template <typename OutT>
__global__ __launch_bounds__(256, 4) void gemm_bias_kernel(
    const bf16_t* __restrict__ A, const bf16_t* __restrict__ WT,
    const float* __restrict__ bias, OutT* __restrict__ C,
    int K, int lda, int ldc)
{
  __shared__ bf16_t Ash[128 * 64];   // [m][k] swizzled, NO padding (lds-dma)
  __shared__ bf16_t Bsh[64 * 64];    // [n][k] swizzled, NO padding

  const int tid  = threadIdx.x;
  const int wave = tid >> 6;
  const int lane = tid & 63;
  const int quad = lane >> 4;
  const int c16  = lane & 15;
  const int wm = wave >> 1;          // 0..1 : row half (64 rows)
  const int wn = wave & 1;           // 0..1 : col half (32 cols)
  const int n0 = blockIdx.x * 64;
  const int m0 = blockIdx.y * 128;

  f32x4 acc[4][2] = {};

  for (int k0 = 0; k0 < K; k0 += 64) {
    __syncthreads();
    // A: 1024 16B-chunks (128 rows x 8); wave stages [wave*256, +256)
    #pragma unroll
    for (int j = 0; j < 4; ++j) {
      int cbase = wave * 256 + j * 64;        // wave-uniform LDS base
      int c = cbase + lane;
      int row = c >> 3;
      int kcl = (c ^ row) & 7;                // xor-permuted chunk fetch
      gld_lds16(A + (size_t)(m0 + row) * lda + k0 + kcl * 8, Ash + cbase * 8);
    }
    // B: 512 16B-chunks (64 rows x 8); wave stages [wave*128, +128)
    #pragma unroll
    for (int j = 0; j < 2; ++j) {
      int cbase = wave * 128 + j * 64;
      int c = cbase + lane;
      int row = c >> 3;
      int kcl = (c ^ row) & 7;
      gld_lds16(WT + (size_t)(n0 + row) * K + k0 + kcl * 8, Bsh + cbase * 8);
    }
    __syncthreads();

    #pragma unroll
    for (int kk = 0; kk < 2; ++kk) {
      bf16x8 af[4], bfr[2];
      #pragma unroll
      for (int rb = 0; rb < 4; ++rb) {
        int row = wm * 64 + rb * 16 + c16;
        int kcp = ((kk * 4 + quad) ^ row) & 7;
        af[rb] = *(const bf16x8*)(Ash + row * 64 + kcp * 8);
      }
      #pragma unroll
      for (int nt = 0; nt < 2; ++nt) {
        int row = wn * 32 + nt * 16 + c16;
        int kcp = ((kk * 4 + quad) ^ row) & 7;
        bfr[nt] = *(const bf16x8*)(Bsh + row * 64 + kcp * 8);
      }
      #pragma unroll
      for (int rb = 0; rb < 4; ++rb)
        #pragma unroll
        for (int nt = 0; nt < 2; ++nt)
          acc[rb][nt] = __builtin_amdgcn_mfma_f32_16x16x32_bf16(af[rb], bfr[nt],
                                                                acc[rb][nt], 0, 0, 0);
    }
  }

  #pragma unroll
  for (int nt = 0; nt < 2; ++nt) {
    int col = n0 + wn * 32 + nt * 16 + c16;
    float bv = bias[col];
    #pragma unroll
    for (int rb = 0; rb < 4; ++rb) {
      int rbase = m0 + wm * 64 + rb * 16 + quad * 4;
      #pragma unroll
      for (int r = 0; r < 4; ++r)
        C[(size_t)(rbase + r) * ldc + col] = (OutT)(acc[rb][nt][r] + bv);
    }
  }
}

// ---------------------------------------------------------------------------
// Causal MQA attention, S^T formulation, 8 waves / 512 threads.
// Waves 0-3 (g=0) own q-tile bx; waves 4-7 (g=1) own q-tile 31-bx. Since
// bx <= 15 <= 31-bx, g0's key range [0,bx] is a PREFIX of g1's [0,31-bx]:
// one shared K/V staging serves both groups, and each group sees its full
// key range -> NO cross-group merge. LDS 35 KB -> 4 blocks/CU (32 waves/CU).
// P: each group uses a disjoint 16B-aligned column half (+g*72) of the dead
// K-tile region. Uniform supersteps per block = 32-bx.
// ---------------------------------------------------------------------------
__global__ __launch_bounds__(512, 8) void mqa_attn_kernel(
    const bf16_t* __restrict__ qkv, const bf16_t* __restrict__ vtg,
    bf16_t* __restrict__ out)
{
  __shared__ bf16_t SM[64 * 136 + 128 * 72];   // Ksh | VTsh (epilogue: O scratch)
  bf16_t* Ksh  = SM;                // K[key][d], stride 136
  bf16_t* VTsh = SM + 64 * 136;     // V^T[d][key], stride 72

  const int tid  = threadIdx.x;
  const int wave = tid >> 6;
  const int g    = wave >> 2;        // q-tile group
  const int wv   = wave & 3;         // q-strip within tile
  const int lane = tid & 63;
  const int quad = lane >> 4;
  const int c16  = lane & 15;
  const int bx = blockIdx.x;         // 0..15
  const int h  = blockIdx.y;
  const int b  = blockIdx.z;
  const float qscale = 0.08838834764831845f * 1.4426950408889634f; // /sqrt(hd)*log2e

  const bf16_t* kbase = qkv + (size_t)b * S_LEN * QKVN + HID;
  const bf16_t* vtb   = vtg + (size_t)b * HD * S_LEN;

  const int qb = g ? (31 - bx) : bx;           // own q-tile
  const int q0 = qb * 64;
  const int qrow = q0 + wv * 16 + c16;

  const bf16_t* qp = qkv + ((size_t)(b * S_LEN + qrow)) * QKVN + h * HD;
  bf16x8 qf[4];
  #pragma unroll
  for (int ks = 0; ks < 4; ++ks) {
    bf16x8 t = *(const bf16x8*)(qp + ks * 32 + quad * 8);
    #pragma unroll
    for (int j = 0; j < 8; ++j) t[j] = (bf16_t)((float)t[j] * qscale);
    qf[ks] = t;
  }

  float m_q = NEG_BIG, l_q = 0.0f;
  f32x4 o[8] = {};
  const int nss = 32 - bx;           // g1's full range; g0 idles after bx

  for (int kt = 0; kt < nss; ++kt) {
    const bool active = (kt <= qb);  // g1: always true

    __syncthreads();
    // shared staging by all 512 threads
    for (int c = tid; c < 1024; c += 512) {
      int key = c >> 4, dc = c & 15;
      *(bf16x8*)(Ksh + key * 136 + dc * 8) =
          *(const bf16x8*)(kbase + (size_t)(kt * 64 + key) * QKVN + dc * 8);
    }
    for (int c = tid; c < 1024; c += 512) {
      int d = c >> 3, kc = c & 7;
      *(bf16x8*)(VTsh + d * 72 + kc * 8) =
          *(const bf16x8*)(vtb + (size_t)d * S_LEN + kt * 64 + kc * 8);
    }
    __syncthreads();

    float p[4][4];
    if (active) {
      f32x4 sacc[4] = {};
      #pragma unroll
      for (int mt = 0; mt < 4; ++mt) {
        #pragma unroll
        for (int ks = 0; ks < 4; ++ks) {
          bf16x8 kf = *(const bf16x8*)(Ksh + (mt * 16 + c16) * 136 + ks * 32 + quad * 8);
          sacc[mt] = __builtin_amdgcn_mfma_f32_16x16x32_bf16(kf, qf[ks], sacc[mt], 0, 0, 0);
        }
      }
      float mx = NEG_BIG;
      if (kt == qb) {   // diagonal tile
        #pragma unroll
        for (int mt = 0; mt < 4; ++mt) {
          #pragma unroll
          for (int r = 0; r < 4; ++r) {
            int key = kt * 64 + mt * 16 + quad * 4 + r;
            float v = sacc[mt][r];
            if (key > qrow) v = NEG_BIG;
            p[mt][r] = v;
            mx = fmaxf(mx, v);
          }
        }
      } else {
        #pragma unroll
        for (int mt = 0; mt < 4; ++mt) {
          #pragma unroll
          for (int r = 0; r < 4; ++r) {
            p[mt][r] = sacc[mt][r];
            mx = fmaxf(mx, sacc[mt][r]);
          }
        }
      }
      mx = fmaxf(mx, __shfl_xor(mx, 16));
      mx = fmaxf(mx, __shfl_xor(mx, 32));

      float mn = fmaxf(m_q, mx);
      float alpha = __builtin_exp2f(m_q - mn);
      m_q = mn;

      float rs = 0.f;
      #pragma unroll
      for (int mt = 0; mt < 4; ++mt) {
        #pragma unroll
        for (int r = 0; r < 4; ++r) {
          float pe = __builtin_exp2f(p[mt][r] - m_q);
          p[mt][r] = pe;
          rs += pe;
        }
      }
      rs += __shfl_xor(rs, 16);
      rs += __shfl_xor(rs, 32);
      l_q = l_q * alpha + rs;
      #pragma unroll
      for (int mt8 = 0; mt8 < 8; ++mt8) {
        #pragma unroll
        for (int r = 0; r < 4; ++r) o[mt8][r] *= alpha;
      }
    }

    __syncthreads();   // all K-tile reads done -> Ksh reusable for P
    if (active) {
      // group g's P half: columns [g*72, g*72+64) of the 136-elem rows
      bf16_t* Pw = Ksh + (wv * 16) * 136 + g * 72;
      #pragma unroll
      for (int mt = 0; mt < 4; ++mt) {
        bf16x4 pk;
        #pragma unroll
        for (int r = 0; r < 4; ++r) pk[r] = (bf16_t)p[mt][r];
        *(bf16x4*)(Pw + c16 * 136 + mt * 16 + quad * 4) = pk;
      }
      bf16x8 pf[2];
      #pragma unroll
      for (int kh = 0; kh < 2; ++kh)
        pf[kh] = *(const bf16x8*)(Pw + c16 * 136 + kh * 32 + quad * 8);
      #pragma unroll
      for (int mt8 = 0; mt8 < 8; ++mt8) {
        #pragma unroll
        for (int kh = 0; kh < 2; ++kh) {
          bf16x8 vf = *(const bf16x8*)(VTsh + (mt8 * 16 + c16) * 72 + kh * 32 + quad * 8);
          o[mt8] = __builtin_amdgcn_mfma_f32_16x16x32_bf16(vf, pf[kh], o[mt8], 0, 0, 0);
        }
      }
    }
  }

  // epilogue: per-wave O^T -> O transpose via private LDS slice; no merge.
  __syncthreads();                          // all PV reads of SM done
  float inv = 1.0f / fmaxf(l_q, 1e-20f);
  bf16_t* Osh = SM + wave * (16 * 136);     // 8 waves x 2176 = 17408 <= 17920
  #pragma unroll
  for (int mt8 = 0; mt8 < 8; ++mt8) {
    bf16x4 pk;
    #pragma unroll
    for (int r = 0; r < 4; ++r) pk[r] = (bf16_t)(o[mt8][r] * inv);
    *(bf16x4*)(Osh + c16 * 136 + mt8 * 16 + quad * 4) = pk;
  }
  // intra-wave only: compiler inserts lgkmcnt wait
  int ql = lane >> 2, dc = lane & 3;
  #pragma unroll
  for (int i = 0; i < 4; ++i) {
    bf16x8 v = *(const bf16x8*)(Osh + ql * 136 + dc * 8 + i * 32);
    *(bf16x8*)(out + ((size_t)(b * S_LEN + q0 + wv * 16 + ql)) * HID
                   + h * HD + dc * 8 + i * 32) = v;
  }
}

extern "C" void kernel_launch(void* const* d_in, const int* in_sizes, int n_in,
                              void* d_out, int out_size, void* d_ws, size_t ws_size,
                              hipStream_t stream) {
  const float* hidden_f   = (const float*)d_in[0];
  // d_in[1] = attention_mask (deterministic causal) -- ignored
  const float* c_attn_w_f = (const float*)d_in[2];
  const float* c_attn_b_f = (const float*)d_in[3];
  const float* c_proj_w_f = (const float*)d_in[4];
  const float* c_proj_b_f = (const float*)d_in[5];
  float* out = (float*)d_out;

  const int M = 2 * S_LEN;                 // 4096
  const int nH  = M * HID;
  const int nWq = HID * QKVN;
  const int nWp = HID * HID;

  bf16_t* hbf   = (bf16_t*)d_ws;
  bf16_t* wqT   = hbf  + nH;               // WT_qkv [2304][2048]
  bf16_t* wpT   = wqT  + nWq;              // WT_proj[2048][2048]
  bf16_t* qkv   = wpT  + nWp;              // [4096][2304]
  bf16_t* attn  = qkv  + (size_t)M * QKVN; // [4096][2048]
  bf16_t* vtg   = attn + (size_t)M * HID;  // V^T [2][128][2048]

  cvt_f32_bf16_kernel<<<nH / 1024, 256, 0, stream>>>(hidden_f, hbf, nH);
  dim3 gt1(QKVN / 64, HID / 32);
  transpose_cvt_kernel<<<gt1, 256, 0, stream>>>(c_attn_w_f, wqT, HID, QKVN);
  dim3 gt2(HID / 64, HID / 32);
  transpose_cvt_kernel<<<gt2, 256, 0, stream>>>(c_proj_w_f, wpT, HID, HID);

  dim3 g1(QKVN / 64, M / 128);             // 36 x 32 = 1152 blocks
  gemm_bias_kernel<bf16_t><<<g1, 256, 0, stream>>>(hbf, wqT, c_attn_b_f, qkv,
                                                   HID, HID, QKVN);

  dim3 gv(S_LEN / 16, 2);
  vt_extract_kernel<<<gv, 256, 0, stream>>>(qkv, vtg);

  dim3 g2(16, NH, 2);                      // 512 blocks x 8 waves
  mqa_attn_kernel<<<g2, 512, 0, stream>>>(qkv, vtg, attn);

  dim3 g3(HID / 64, M / 128);              // 32 x 32 = 1024 blocks
  gemm_bias_kernel<float><<<g3, 256, 0, stream>>>(attn, wpT, c_proj_b_f, out,
                                                  HID, HID, HID);
}